// Round 1
// baseline (1416.209 us; speedup 1.0000x reference)
//
#include <hip/hip_runtime.h>
#include <hip/hip_bf16.h>

typedef __bf16 bf16x8 __attribute__((ext_vector_type(8)));
typedef __bf16 bf16x4 __attribute__((ext_vector_type(4)));
typedef float  f32x4  __attribute__((ext_vector_type(4)));

#define KEPS 1e-8f
#define BM 128
#define BN 128
#define BK 64

// ---------------- 1) row L2-normalize: fp32 norms + bf16 normalized copy ----
__global__ __launch_bounds__(256) void k_normalize(
    const float* __restrict__ in, __bf16* __restrict__ xb,
    float* __restrict__ norms, unsigned long long* __restrict__ best,
    float* __restrict__ sum, int D)
{
    const int row = blockIdx.x;
    const int t = threadIdx.x;
    const float4* inr = (const float4*)(in + (size_t)row * D);
    float4 v = inr[t];                       // D=1024 -> 256 float4
    float ss = v.x*v.x + v.y*v.y + v.z*v.z + v.w*v.w;
    for (int off = 32; off; off >>= 1) ss += __shfl_down(ss, off);
    __shared__ float red[4];
    const int lane = t & 63, wave = t >> 6;
    if (lane == 0) red[wave] = ss;
    __syncthreads();
    const float total = red[0] + red[1] + red[2] + red[3];
    const float nrm = sqrtf(total);
    const float inv = 1.0f / fmaxf(nrm, KEPS);
    bf16x4 o;
    o.x = (__bf16)(v.x * inv); o.y = (__bf16)(v.y * inv);
    o.z = (__bf16)(v.z * inv); o.w = (__bf16)(v.w * inv);
    ((bf16x4*)(xb + (size_t)row * D))[t] = o;
    if (t == 0) {
        norms[row] = nrm;
        best[row] = 0ull;                    // any real packed key beats 0
        if (row == 0) sum[0] = 0.0f;
    }
}

// ---------------- 2) x x^T tile GEMM with fused per-row argmax --------------
// 128x128 tile, 4 waves (2x2 of 64x64), mfma_f32_16x16x32_bf16, BK=64.
// LDS layout XOR-swizzled at 16B-chunk granularity (global_load_lds keeps
// lane-contiguous LDS dests; swizzle moved to the *global* column instead).
__global__ __launch_bounds__(256) void k_gemm_argmax(
    const __bf16* __restrict__ xb, unsigned long long* __restrict__ best,
    int N, int D)
{
    __shared__ __bf16 lds[(BM + BN) * BK];   // 32 KiB
    const int t    = threadIdx.x;
    const int lane = t & 63;
    const int wave = t >> 6;
    const int quad = lane >> 4;
    const int c16  = lane & 15;
    const int wm   = (wave >> 1) * 64;
    const int wn   = (wave & 1) * 64;
    const int m0   = blockIdx.y * BM;
    const int n0   = blockIdx.x * BN;

    __bf16* Al = lds;
    __bf16* Bl = lds + BM * BK;

    f32x4 acc[4][4] = {};

    const int row_s = t >> 3;   // staging: chunk c = it*256+t -> row = it*32 + (t>>3)
    const int c8s   = t & 7;    // stored chunk-col; global chunk-col = c8s ^ (row&7)

    for (int kt = 0; kt < D; kt += BK) {
        __syncthreads();
        #pragma unroll
        for (int it = 0; it < 4; ++it) {
            const int row    = it * 32 + row_s;
            const int gcol   = ((c8s ^ (row & 7)) * 8) + kt;   // element col
            const int lchunk = (it * 256 + t) * 8;             // element offset in LDS
            __builtin_amdgcn_global_load_lds(
                (const __attribute__((address_space(1))) void*)(xb + (size_t)(m0 + row) * D + gcol),
                (__attribute__((address_space(3))) void*)(Al + lchunk), 16, 0, 0);
            __builtin_amdgcn_global_load_lds(
                (const __attribute__((address_space(1))) void*)(xb + (size_t)(n0 + row) * D + gcol),
                (__attribute__((address_space(3))) void*)(Bl + lchunk), 16, 0, 0);
        }
        __syncthreads();
        const int swz = c16 & 7;
        #pragma unroll
        for (int ks = 0; ks < 2; ++ks) {
            bf16x8 a[4], b[4];
            const int col = (ks * 4 + quad) ^ swz;             // swizzled chunk col
            #pragma unroll
            for (int i = 0; i < 4; ++i)
                a[i] = *(const bf16x8*)(Al + ((wm + i * 16 + c16) * 8 + col) * 8);
            #pragma unroll
            for (int i = 0; i < 4; ++i)
                b[i] = *(const bf16x8*)(Bl + ((wn + i * 16 + c16) * 8 + col) * 8);
            #pragma unroll
            for (int i = 0; i < 4; ++i)
                #pragma unroll
                for (int j = 0; j < 4; ++j)
                    acc[i][j] = __builtin_amdgcn_mfma_f32_16x16x32_bf16(a[i], b[j], acc[i][j], 0, 0, 0);
        }
    }

    // Epilogue: per-row argmax over this block's 128 cols, then one atomicMax.
    // C/D layout (m89-verified): col = lane&15, row = quad*4 + reg.
    #pragma unroll
    for (int i = 0; i < 4; ++i) {
        #pragma unroll
        for (int r = 0; r < 4; ++r) {
            const int grow = m0 + wm + i * 16 + quad * 4 + r;
            float v = -3.0f; unsigned c = 0xFFFFFFFFu;
            #pragma unroll
            for (int j = 0; j < 4; ++j) {
                const int col = n0 + wn + j * 16 + c16;
                const float val = acc[i][j][r];
                if (col != grow && (val > v || (val == v && (unsigned)col < c))) {
                    v = val; c = (unsigned)col;
                }
            }
            // reduce across the quad's 16 lanes (one row lives in one quad)
            for (int off = 8; off; off >>= 1) {
                const float    ov = __shfl_xor(v, off);
                const unsigned oc = (unsigned)__shfl_xor((int)c, off);
                if (ov > v || (ov == v && oc < c)) { v = ov; c = oc; }
            }
            if (c16 == 0) {
                unsigned ub = __float_as_uint(v);
                ub = (ub & 0x80000000u) ? ~ub : (ub | 0x80000000u); // monotonic map
                const unsigned long long key =
                    ((unsigned long long)ub << 32) | (unsigned long long)(~c);
                atomicMax(best + grow, key);
            }
        }
    }
}

// ---------------- 3) pairwise distance + log, accumulate --------------------
__global__ __launch_bounds__(256) void k_dist(
    const float* __restrict__ in, const float* __restrict__ norms,
    const unsigned long long* __restrict__ best, float* __restrict__ sum, int D)
{
    const int row = blockIdx.x;
    const int t = threadIdx.x;
    const unsigned long long key = best[row];
    const int nb = (int)(~(unsigned)key);        // recover neighbor index
    const float invi = 1.0f / fmaxf(norms[row], KEPS);
    const float invj = 1.0f / fmaxf(norms[nb], KEPS);
    const float4* xi = (const float4*)(in + (size_t)row * D);
    const float4* xj = (const float4*)(in + (size_t)nb * D);
    const float4 a = xi[t], b = xj[t];
    const float dx = a.x * invi - b.x * invj + KEPS;
    const float dy = a.y * invi - b.y * invj + KEPS;
    const float dz = a.z * invi - b.z * invj + KEPS;
    const float dw = a.w * invi - b.w * invj + KEPS;
    float ss = dx*dx + dy*dy + dz*dz + dw*dw;
    for (int off = 32; off; off >>= 1) ss += __shfl_down(ss, off);
    __shared__ float red[4];
    const int lane = t & 63, wave = t >> 6;
    if (lane == 0) red[wave] = ss;
    __syncthreads();
    if (t == 0) {
        const float tot = red[0] + red[1] + red[2] + red[3];
        atomicAdd(sum, logf(sqrtf(tot) + KEPS));
    }
}

// ---------------- 4) finalize ----------------------------------------------
__global__ void k_final(const float* __restrict__ sum, float* __restrict__ out, float invN)
{
    out[0] = -sum[0] * invN;
}

extern "C" void kernel_launch(void* const* d_in, const int* in_sizes, int n_in,
                              void* d_out, int out_size, void* d_ws, size_t ws_size,
                              hipStream_t stream)
{
    const float* in = (const float*)d_in[0];
    const int D = 1024;
    const int N = in_sizes[0] / D;               // 16384

    char* ws = (char*)d_ws;
    __bf16* xb = (__bf16*)ws;                                    // N*D*2   = 32 MiB
    size_t off = (size_t)N * D * 2;
    float* norms = (float*)(ws + off);           off += (size_t)N * 4;
    unsigned long long* best = (unsigned long long*)(ws + off); off += (size_t)N * 8;
    float* sum = (float*)(ws + off);
    float* out = (float*)d_out;

    k_normalize<<<N, 256, 0, stream>>>(in, xb, norms, best, sum, D);
    dim3 grid(N / BN, N / BM);
    k_gemm_argmax<<<grid, 256, 0, stream>>>(xb, best, N, D);
    k_dist<<<N, 256, 0, stream>>>(in, norms, best, sum, D);
    k_final<<<1, 1, 0, stream>>>(sum, out, 1.0f / (float)N);
}

// Round 2
// 895.602 us; speedup vs baseline: 1.5813x; 1.5813x over previous
//
#include <hip/hip_runtime.h>
#include <hip/hip_bf16.h>

typedef __bf16 bf16x8 __attribute__((ext_vector_type(8)));
typedef __bf16 bf16x4 __attribute__((ext_vector_type(4)));
typedef float  f32x4  __attribute__((ext_vector_type(4)));

#define KEPS 1e-8f
#define BM 128
#define BN 128
#define BK 64

// ---------------- 1) row L2-normalize: fp32 norms + bf16 normalized copy ----
__global__ __launch_bounds__(256) void k_normalize(
    const float* __restrict__ in, __bf16* __restrict__ xb,
    float* __restrict__ norms, unsigned long long* __restrict__ best,
    float* __restrict__ sum, int D)
{
    const int row = blockIdx.x;
    const int t = threadIdx.x;
    const float4* inr = (const float4*)(in + (size_t)row * D);
    float4 v = inr[t];                       // D=1024 -> 256 float4
    float ss = v.x*v.x + v.y*v.y + v.z*v.z + v.w*v.w;
    for (int off = 32; off; off >>= 1) ss += __shfl_down(ss, off);
    __shared__ float red[4];
    const int lane = t & 63, wave = t >> 6;
    if (lane == 0) red[wave] = ss;
    __syncthreads();
    const float total = red[0] + red[1] + red[2] + red[3];
    const float nrm = sqrtf(total);
    const float inv = 1.0f / fmaxf(nrm, KEPS);
    bf16x4 o;
    o.x = (__bf16)(v.x * inv); o.y = (__bf16)(v.y * inv);
    o.z = (__bf16)(v.z * inv); o.w = (__bf16)(v.w * inv);
    ((bf16x4*)(xb + (size_t)row * D))[t] = o;
    if (t == 0) {
        norms[row] = nrm;
        best[row] = 0ull;                    // any real packed key beats 0
        if (row == 0) sum[0] = 0.0f;
    }
}

__device__ __forceinline__ unsigned long long pack_key(float v, unsigned idx)
{
    unsigned ub = __float_as_uint(v);
    ub = (ub & 0x80000000u) ? ~ub : (ub | 0x80000000u); // monotonic map
    return ((unsigned long long)ub << 32) | (unsigned long long)(~idx);
}

// ---------------- 2) x x^T upper-triangular GEMM with fused argmax ----------
// Symmetric Gram matrix: only blocks with bx >= by are computed. Off-diagonal
// blocks reduce BOTH row-wise (argmax over cols for rows m0..) and col-wise
// (argmax over rows for cols n0..), halving total MFMA work.
// 128x128 tile, 4 waves (2x2 of 64x64), mfma_f32_16x16x32_bf16, BK=64.
// LDS XOR-swizzled at 16B-chunk granularity (swizzle applied to the *global*
// column so global_load_lds lane-contiguity is preserved).
__global__ __launch_bounds__(256) void k_gemm_argmax(
    const __bf16* __restrict__ xb, unsigned long long* __restrict__ best,
    int N, int D, int T)
{
    // triangular mapping: p -> (by, bx), bx >= by
    const int p = blockIdx.x;
    const float tf = (float)T + 0.5f;
    int by = (int)(tf - sqrtf(tf * tf - 2.0f * (float)p));
    while (by > 0 && p < by * T - by * (by - 1) / 2) --by;
    while (p >= (by + 1) * T - (by + 1) * by / 2) ++by;
    const int bx = by + (p - (by * T - by * (by - 1) / 2));

    __shared__ __bf16 lds[(BM + BN) * BK];   // 32 KiB
    const int t    = threadIdx.x;
    const int lane = t & 63;
    const int wave = t >> 6;
    const int quad = lane >> 4;
    const int c16  = lane & 15;
    const int wm   = (wave >> 1) * 64;
    const int wn   = (wave & 1) * 64;
    const int m0   = by * BM;
    const int n0   = bx * BN;

    __bf16* Al = lds;
    __bf16* Bl = lds + BM * BK;

    f32x4 acc[4][4] = {};

    const int row_s = t >> 3;   // staging: chunk c = it*256+t -> row = it*32 + (t>>3)
    const int c8s   = t & 7;    // stored chunk-col; global chunk-col = c8s ^ (row&7)

    for (int kt = 0; kt < D; kt += BK) {
        __syncthreads();
        #pragma unroll
        for (int it = 0; it < 4; ++it) {
            const int row    = it * 32 + row_s;
            const int gcol   = ((c8s ^ (row & 7)) * 8) + kt;   // element col
            const int lchunk = (it * 256 + t) * 8;             // element offset in LDS
            __builtin_amdgcn_global_load_lds(
                (const __attribute__((address_space(1))) void*)(xb + (size_t)(m0 + row) * D + gcol),
                (__attribute__((address_space(3))) void*)(Al + lchunk), 16, 0, 0);
            __builtin_amdgcn_global_load_lds(
                (const __attribute__((address_space(1))) void*)(xb + (size_t)(n0 + row) * D + gcol),
                (__attribute__((address_space(3))) void*)(Bl + lchunk), 16, 0, 0);
        }
        __syncthreads();
        const int swz = c16 & 7;
        #pragma unroll
        for (int ks = 0; ks < 2; ++ks) {
            bf16x8 a[4], b[4];
            const int col = (ks * 4 + quad) ^ swz;             // swizzled chunk col
            #pragma unroll
            for (int i = 0; i < 4; ++i)
                a[i] = *(const bf16x8*)(Al + ((wm + i * 16 + c16) * 8 + col) * 8);
            #pragma unroll
            for (int i = 0; i < 4; ++i)
                b[i] = *(const bf16x8*)(Bl + ((wn + i * 16 + c16) * 8 + col) * 8);
            #pragma unroll
            for (int i = 0; i < 4; ++i)
                #pragma unroll
                for (int j = 0; j < 4; ++j)
                    acc[i][j] = __builtin_amdgcn_mfma_f32_16x16x32_bf16(a[i], b[j], acc[i][j], 0, 0, 0);
        }
    }

    // ---- row-wise argmax (rows m0+..., over this block's 128 cols) ----
    // C/D layout (m89-verified): col = lane&15, row = quad*4 + reg.
    #pragma unroll
    for (int i = 0; i < 4; ++i) {
        #pragma unroll
        for (int r = 0; r < 4; ++r) {
            const int grow = m0 + wm + i * 16 + quad * 4 + r;
            float v = -3.0f; unsigned c = 0xFFFFFFFFu;
            #pragma unroll
            for (int j = 0; j < 4; ++j) {
                const int col = n0 + wn + j * 16 + c16;
                const float val = acc[i][j][r];
                if (col != grow && (val > v || (val == v && (unsigned)col < c))) {
                    v = val; c = (unsigned)col;
                }
            }
            // reduce across the quad's 16 lanes (one row lives in one quad)
            for (int off = 8; off; off >>= 1) {
                const float    ov = __shfl_xor(v, off);
                const unsigned oc = (unsigned)__shfl_xor((int)c, off);
                if (ov > v || (ov == v && oc < c)) { v = ov; c = oc; }
            }
            if (c16 == 0) atomicMax(best + grow, pack_key(v, c));
        }
    }

    // ---- col-wise argmax (cols n0+..., over this block's 128 rows) ----
    // Off-diagonal only: diagonal blocks' pairs are fully covered by the row
    // pass (both orderings of each pair are materialized in the full tile).
    if (bx != by) {
        #pragma unroll
        for (int j = 0; j < 4; ++j) {
            const int gcol = n0 + wn + j * 16 + c16;
            float v = -3.0f; unsigned c = 0xFFFFFFFFu;
            #pragma unroll
            for (int i = 0; i < 4; ++i) {
                #pragma unroll
                for (int r = 0; r < 4; ++r) {
                    const int grow = m0 + wm + i * 16 + quad * 4 + r;
                    const float val = acc[i][j][r];
                    if (val > v || (val == v && (unsigned)grow < c)) {
                        v = val; c = (unsigned)grow;
                    }
                }
            }
            // reduce across the 4 lanes sharing c16 (quads: xor 16, 32)
            for (int off = 32; off >= 16; off >>= 1) {
                const float    ov = __shfl_xor(v, off);
                const unsigned oc = (unsigned)__shfl_xor((int)c, off);
                if (ov > v || (ov == v && oc < c)) { v = ov; c = oc; }
            }
            if (quad == 0) atomicMax(best + gcol, pack_key(v, c));
        }
    }
}

// ---------------- 3) pairwise distance + log, accumulate --------------------
__global__ __launch_bounds__(256) void k_dist(
    const float* __restrict__ in, const float* __restrict__ norms,
    const unsigned long long* __restrict__ best, float* __restrict__ sum, int D)
{
    const int row = blockIdx.x;
    const int t = threadIdx.x;
    const unsigned long long key = best[row];
    const int nb = (int)(~(unsigned)key);        // recover neighbor index
    const float invi = 1.0f / fmaxf(norms[row], KEPS);
    const float invj = 1.0f / fmaxf(norms[nb], KEPS);
    const float4* xi = (const float4*)(in + (size_t)row * D);
    const float4* xj = (const float4*)(in + (size_t)nb * D);
    const float4 a = xi[t], b = xj[t];
    const float dx = a.x * invi - b.x * invj + KEPS;
    const float dy = a.y * invi - b.y * invj + KEPS;
    const float dz = a.z * invi - b.z * invj + KEPS;
    const float dw = a.w * invi - b.w * invj + KEPS;
    float ss = dx*dx + dy*dy + dz*dz + dw*dw;
    for (int off = 32; off; off >>= 1) ss += __shfl_down(ss, off);
    __shared__ float red[4];
    const int lane = t & 63, wave = t >> 6;
    if (lane == 0) red[wave] = ss;
    __syncthreads();
    if (t == 0) {
        const float tot = red[0] + red[1] + red[2] + red[3];
        atomicAdd(sum, logf(sqrtf(tot) + KEPS));
    }
}

// ---------------- 4) finalize ----------------------------------------------
__global__ void k_final(const float* __restrict__ sum, float* __restrict__ out, float invN)
{
    out[0] = -sum[0] * invN;
}

extern "C" void kernel_launch(void* const* d_in, const int* in_sizes, int n_in,
                              void* d_out, int out_size, void* d_ws, size_t ws_size,
                              hipStream_t stream)
{
    const float* in = (const float*)d_in[0];
    const int D = 1024;
    const int N = in_sizes[0] / D;               // 16384

    char* ws = (char*)d_ws;
    __bf16* xb = (__bf16*)ws;                                    // N*D*2   = 32 MiB
    size_t off = (size_t)N * D * 2;
    float* norms = (float*)(ws + off);           off += (size_t)N * 4;
    unsigned long long* best = (unsigned long long*)(ws + off); off += (size_t)N * 8;
    float* sum = (float*)(ws + off);
    float* out = (float*)d_out;

    k_normalize<<<N, 256, 0, stream>>>(in, xb, norms, best, sum, D);
    const int T = N / BM;                        // 128 tiles per dim
    const int P = T * (T + 1) / 2;               // 8256 upper-tri blocks
    k_gemm_argmax<<<P, 256, 0, stream>>>(xb, best, N, D, T);
    k_dist<<<N, 256, 0, stream>>>(in, norms, best, sum, D);
    k_final<<<1, 1, 0, stream>>>(sum, out, 1.0f / (float)N);
}

// Round 3
// 771.960 us; speedup vs baseline: 1.8346x; 1.1602x over previous
//
#include <hip/hip_runtime.h>
#include <hip/hip_bf16.h>

typedef __bf16 bf16x8 __attribute__((ext_vector_type(8)));
typedef __bf16 bf16x4 __attribute__((ext_vector_type(4)));
typedef float  f32x4  __attribute__((ext_vector_type(4)));

#define KEPS 1e-8f
#define BM 256
#define BN 128
#define BK 64

// ---------------- 1) row L2-normalize: fp32 norms + bf16 normalized copy ----
__global__ __launch_bounds__(256) void k_normalize(
    const float* __restrict__ in, __bf16* __restrict__ xb,
    float* __restrict__ norms, unsigned long long* __restrict__ best,
    float* __restrict__ sum, int D)
{
    const int row = blockIdx.x;
    const int t = threadIdx.x;
    const float4* inr = (const float4*)(in + (size_t)row * D);
    float4 v = inr[t];                       // D=1024 -> 256 float4
    float ss = v.x*v.x + v.y*v.y + v.z*v.z + v.w*v.w;
    for (int off = 32; off; off >>= 1) ss += __shfl_down(ss, off);
    __shared__ float red[4];
    const int lane = t & 63, wave = t >> 6;
    if (lane == 0) red[wave] = ss;
    __syncthreads();
    const float total = red[0] + red[1] + red[2] + red[3];
    const float nrm = sqrtf(total);
    const float inv = 1.0f / fmaxf(nrm, KEPS);
    bf16x4 o;
    o.x = (__bf16)(v.x * inv); o.y = (__bf16)(v.y * inv);
    o.z = (__bf16)(v.z * inv); o.w = (__bf16)(v.w * inv);
    ((bf16x4*)(xb + (size_t)row * D))[t] = o;
    if (t == 0) {
        norms[row] = nrm;
        best[row] = 0ull;                    // any real packed key beats 0
        if (row == 0) sum[0] = 0.0f;
    }
}

__device__ __forceinline__ unsigned long long pack_key(float v, unsigned idx)
{
    unsigned ub = __float_as_uint(v);
    ub = (ub & 0x80000000u) ? ~ub : (ub | 0x80000000u); // monotonic map
    return ((unsigned long long)ub << 32) | (unsigned long long)(~idx);
}

// ---------------- 2) x x^T triangular GEMM with fused argmax ----------------
// BM=256 x BN=128 tile, 4 waves, each wave owns 128x64 (acc 8x4 of f32x4).
// Symmetric Gram matrix: only blocks with bx >= 2*by computed. Every
// unordered pair (i<j) is covered: row-pass at block (i>>8, j>>7) [valid since
// 2*(i>>8) <= i>>7 <= j>>7] and col-pass at block (i>>8, j>>7) covers best[j].
// Duplicated coverage (diagonal wedge) is harmless under atomicMax; diagonal
// cells masked in both passes.
// LDS XOR-swizzled at 16B-chunk granularity (swizzle applied to the *global*
// column so global_load_lds lane-contiguity is preserved).
__global__ __launch_bounds__(256, 2) void k_gemm_argmax(
    const __bf16* __restrict__ xb, unsigned long long* __restrict__ best,
    int N, int D, int TX)
{
    // triangular mapping: p -> (by, bx), bx >= 2*by
    // off(by) = sum_{r<by} (TX - 2r) = by*(TX+1-by)
    const int p = blockIdx.x;
    const float c1 = (float)(TX + 1);
    int by = (int)((c1 - sqrtf(c1 * c1 - 4.0f * (float)p)) * 0.5f);
    while (by > 0 && p < by * (TX + 1 - by)) --by;
    while (p >= (by + 1) * (TX - by)) ++by;
    const int bx = 2 * by + (p - by * (TX + 1 - by));

    __shared__ __bf16 lds[(BM + BN) * BK];   // 48 KiB
    const int t    = threadIdx.x;
    const int lane = t & 63;
    const int wave = t >> 6;
    const int quad = lane >> 4;
    const int c16  = lane & 15;
    const int wrow = (wave >> 1) * 128;      // wave's row-half of the 256
    const int wcol = (wave & 1) * 64;        // wave's col-half of the 128
    const int m0   = by * BM;
    const int n0   = bx * BN;

    __bf16* Al = lds;
    __bf16* Bl = lds + BM * BK;

    f32x4 acc[8][4] = {};

    const int row_s = t >> 3;   // staging: chunk c = it*256+t -> row = it*32 + (t>>3)
    const int c8s   = t & 7;    // stored chunk-col; global chunk-col = c8s ^ (row&7)

    for (int kt = 0; kt < D; kt += BK) {
        __syncthreads();
        #pragma unroll
        for (int it = 0; it < 8; ++it) {     // A: 256 rows
            const int row    = it * 32 + row_s;
            const int gcol   = ((c8s ^ (row & 7)) * 8) + kt;
            const int lchunk = (it * 256 + t) * 8;
            __builtin_amdgcn_global_load_lds(
                (const __attribute__((address_space(1))) void*)(xb + (size_t)(m0 + row) * D + gcol),
                (__attribute__((address_space(3))) void*)(Al + lchunk), 16, 0, 0);
        }
        #pragma unroll
        for (int it = 0; it < 4; ++it) {     // B: 128 rows
            const int row    = it * 32 + row_s;
            const int gcol   = ((c8s ^ (row & 7)) * 8) + kt;
            const int lchunk = (it * 256 + t) * 8;
            __builtin_amdgcn_global_load_lds(
                (const __attribute__((address_space(1))) void*)(xb + (size_t)(n0 + row) * D + gcol),
                (__attribute__((address_space(3))) void*)(Bl + lchunk), 16, 0, 0);
        }
        __syncthreads();
        const int swz = c16 & 7;
        #pragma unroll
        for (int ks = 0; ks < 2; ++ks) {
            bf16x8 a[8], b[4];
            const int col = (ks * 4 + quad) ^ swz;             // swizzled chunk col
            #pragma unroll
            for (int i = 0; i < 8; ++i)
                a[i] = *(const bf16x8*)(Al + ((wrow + i * 16 + c16) * 8 + col) * 8);
            #pragma unroll
            for (int j = 0; j < 4; ++j)
                b[j] = *(const bf16x8*)(Bl + ((wcol + j * 16 + c16) * 8 + col) * 8);
            #pragma unroll
            for (int i = 0; i < 8; ++i)
                #pragma unroll
                for (int j = 0; j < 4; ++j)
                    acc[i][j] = __builtin_amdgcn_mfma_f32_16x16x32_bf16(a[i], b[j], acc[i][j], 0, 0, 0);
        }
    }

    // ---- row-wise argmax (this wave's 128 rows, over its 64 cols) ----
    // C/D layout (m89-verified): col = lane&15, row = quad*4 + reg.
    #pragma unroll
    for (int i = 0; i < 8; ++i) {
        #pragma unroll
        for (int r = 0; r < 4; ++r) {
            const int grow = m0 + wrow + i * 16 + quad * 4 + r;
            float v = -3.0f; unsigned c = 0xFFFFFFFFu;
            #pragma unroll
            for (int j = 0; j < 4; ++j) {
                const int col = n0 + wcol + j * 16 + c16;
                const float val = acc[i][j][r];
                if (col != grow && (val > v || (val == v && (unsigned)col < c))) {
                    v = val; c = (unsigned)col;
                }
            }
            // reduce across the quad's 16 lanes (one row lives in one quad)
            for (int off = 8; off; off >>= 1) {
                const float    ov = __shfl_xor(v, off);
                const unsigned oc = (unsigned)__shfl_xor((int)c, off);
                if (ov > v || (ov == v && oc < c)) { v = ov; c = oc; }
            }
            if (c16 == 0) atomicMax(best + grow, pack_key(v, c));
        }
    }

    // ---- col-wise argmax (this wave's 64 cols, over its 128 rows) ----
    #pragma unroll
    for (int j = 0; j < 4; ++j) {
        const int gcol = n0 + wcol + j * 16 + c16;
        float v = -3.0f; unsigned c = 0xFFFFFFFFu;
        #pragma unroll
        for (int i = 0; i < 8; ++i) {
            #pragma unroll
            for (int r = 0; r < 4; ++r) {
                const int grow = m0 + wrow + i * 16 + quad * 4 + r;
                const float val = acc[i][j][r];
                if (grow != gcol && (val > v || (val == v && (unsigned)grow < c))) {
                    v = val; c = (unsigned)grow;
                }
            }
        }
        // reduce across the 4 quads (lanes sharing c16): xor 16, 32
        for (int off = 32; off >= 16; off >>= 1) {
            const float    ov = __shfl_xor(v, off);
            const unsigned oc = (unsigned)__shfl_xor((int)c, off);
            if (ov > v || (ov == v && oc < c)) { v = ov; c = oc; }
        }
        if (quad == 0) atomicMax(best + gcol, pack_key(v, c));
    }
}

// ---------------- 3) pairwise distance + log, accumulate --------------------
__global__ __launch_bounds__(256) void k_dist(
    const float* __restrict__ in, const float* __restrict__ norms,
    const unsigned long long* __restrict__ best, float* __restrict__ sum, int D)
{
    const int row = blockIdx.x;
    const int t = threadIdx.x;
    const unsigned long long key = best[row];
    const int nb = (int)(~(unsigned)key);        // recover neighbor index
    const float invi = 1.0f / fmaxf(norms[row], KEPS);
    const float invj = 1.0f / fmaxf(norms[nb], KEPS);
    const float4* xi = (const float4*)(in + (size_t)row * D);
    const float4* xj = (const float4*)(in + (size_t)nb * D);
    const float4 a = xi[t], b = xj[t];
    const float dx = a.x * invi - b.x * invj + KEPS;
    const float dy = a.y * invi - b.y * invj + KEPS;
    const float dz = a.z * invi - b.z * invj + KEPS;
    const float dw = a.w * invi - b.w * invj + KEPS;
    float ss = dx*dx + dy*dy + dz*dz + dw*dw;
    for (int off = 32; off; off >>= 1) ss += __shfl_down(ss, off);
    __shared__ float red[4];
    const int lane = t & 63, wave = t >> 6;
    if (lane == 0) red[wave] = ss;
    __syncthreads();
    if (t == 0) {
        const float tot = red[0] + red[1] + red[2] + red[3];
        atomicAdd(sum, logf(sqrtf(tot) + KEPS));
    }
}

// ---------------- 4) finalize ----------------------------------------------
__global__ void k_final(const float* __restrict__ sum, float* __restrict__ out, float invN)
{
    out[0] = -sum[0] * invN;
}

extern "C" void kernel_launch(void* const* d_in, const int* in_sizes, int n_in,
                              void* d_out, int out_size, void* d_ws, size_t ws_size,
                              hipStream_t stream)
{
    const float* in = (const float*)d_in[0];
    const int D = 1024;
    const int N = in_sizes[0] / D;               // 16384

    char* ws = (char*)d_ws;
    __bf16* xb = (__bf16*)ws;                                    // N*D*2   = 32 MiB
    size_t off = (size_t)N * D * 2;
    float* norms = (float*)(ws + off);           off += (size_t)N * 4;
    unsigned long long* best = (unsigned long long*)(ws + off); off += (size_t)N * 8;
    float* sum = (float*)(ws + off);
    float* out = (float*)d_out;

    k_normalize<<<N, 256, 0, stream>>>(in, xb, norms, best, sum, D);
    const int TY = N / BM;                       // 64 row-tiles
    const int TX = N / BN;                       // 128 col-tiles
    int P = 0;
    for (int by = 0; by < TY; ++by) P += TX - 2 * by;   // 4160 blocks
    k_gemm_argmax<<<P, 256, 0, stream>>>(xb, best, N, D, TX);
    k_dist<<<N, 256, 0, stream>>>(in, norms, best, sum, D);
    k_final<<<1, 1, 0, stream>>>(sum, out, 1.0f / (float)N);
}

// Round 4
// 518.272 us; speedup vs baseline: 2.7326x; 1.4895x over previous
//
#include <hip/hip_runtime.h>

typedef float f32x4 __attribute__((ext_vector_type(4)));
typedef unsigned char uchar;

#define KEPS 1e-8f
#define BM 256
#define BN 128
#define BK 128   // fp8 bytes == elements; 8 K-iterations over D=1024

// ---------------- 1) row L2-normalize: fp32 norms + fp8 e4m3 copy -----------
__global__ __launch_bounds__(256) void k_normalize(
    const float* __restrict__ in, uchar* __restrict__ xq,
    float* __restrict__ norms, unsigned long long* __restrict__ best,
    float* __restrict__ psum, int D)
{
    const int row = blockIdx.x;
    const int t = threadIdx.x;
    const float4* inr = (const float4*)(in + (size_t)row * D);
    float4 v = inr[t];                       // D=1024 -> 256 float4
    float ss = v.x*v.x + v.y*v.y + v.z*v.z + v.w*v.w;
    for (int off = 32; off; off >>= 1) ss += __shfl_down(ss, off);
    __shared__ float red[4];
    const int lane = t & 63, wave = t >> 6;
    if (lane == 0) red[wave] = ss;
    __syncthreads();
    const float total = red[0] + red[1] + red[2] + red[3];
    const float nrm = sqrtf(total);
    const float inv = 1.0f / fmaxf(nrm, KEPS);
    // pack 4 floats -> 4 fp8 e4m3 bytes (OCP, HW saturating convert)
    unsigned r = 0;
    r = __builtin_amdgcn_cvt_pk_fp8_f32(v.x * inv, v.y * inv, r, 0);
    r = __builtin_amdgcn_cvt_pk_fp8_f32(v.z * inv, v.w * inv, r, 1);
    ((unsigned*)(xq + (size_t)row * D))[t] = r;
    if (t == 0) {
        norms[row] = nrm;
        best[row] = 0ull;                    // any real packed key beats 0
    }
    if (row < 256 && t == 1) psum[row * 16] = 0.0f;   // cache-line-padded partials
}

__device__ __forceinline__ unsigned long long pack_key(float v, unsigned idx)
{
    unsigned ub = __float_as_uint(v);
    ub = (ub & 0x80000000u) ? ~ub : (ub | 0x80000000u); // monotonic map
    return ((unsigned long long)ub << 32) | (unsigned long long)(~idx);
}

// ---------------- 2) x x^T triangular fp8 GEMM with fused argmax ------------
// BM=256 x BN=128 tile, 4 waves, each wave owns 128x64 (acc 8x4 of f32x4).
// fp8 e4m3, mfma_f32_16x16x32_fp8_fp8 (A/B as i64: m=lane&15, k=quad*8+byte).
// BK=128 bytes -> 8 K-iterations (half the barrier drains of bf16 BK=64).
// Triangular covering: only blocks with bx >= 2*by; row-pass + col-pass per
// block covers every unordered pair; duplicates harmless under atomicMax.
// LDS XOR-swizzled at 16B-chunk granularity (swizzle applied to the *global*
// column so global_load_lds lane-contiguity is preserved).
__global__ __launch_bounds__(256, 2) void k_gemm_argmax(
    const uchar* __restrict__ xq, unsigned long long* __restrict__ best,
    int N, int D, int TX)
{
    // triangular mapping: p -> (by, bx), bx >= 2*by ; off(by) = by*(TX+1-by)
    const int p = blockIdx.x;
    const float c1 = (float)(TX + 1);
    int by = (int)((c1 - sqrtf(c1 * c1 - 4.0f * (float)p)) * 0.5f);
    while (by > 0 && p < by * (TX + 1 - by)) --by;
    while (p >= (by + 1) * (TX - by)) ++by;
    const int bx = 2 * by + (p - by * (TX + 1 - by));

    __shared__ uchar lds[(BM + BN) * BK];    // 48 KiB
    const int t    = threadIdx.x;
    const int lane = t & 63;
    const int wave = t >> 6;
    const int quad = lane >> 4;
    const int c16  = lane & 15;
    const int wrow = (wave >> 1) * 128;      // wave's row-half of the 256
    const int wcol = (wave & 1) * 64;        // wave's col-half of the 128
    const int m0   = by * BM;
    const int n0   = bx * BN;

    uchar* Al = lds;
    uchar* Bl = lds + BM * BK;

    f32x4 acc[8][4] = {};

    const int row_s = t >> 3;   // staging: chunk c = it*256+t -> row = it*32 + (t>>3)
    const int c8s   = t & 7;    // stored chunk-col; global chunk-col = c8s ^ (row&7)

    for (int kt = 0; kt < D; kt += BK) {
        __syncthreads();
        #pragma unroll
        for (int it = 0; it < 8; ++it) {     // A: 256 rows x 128 B = 2048 chunks
            const int row    = it * 32 + row_s;
            const int gcol   = ((c8s ^ (row & 7)) * 16) + kt;   // byte col
            const int lchunk = (it * 256 + t) * 16;             // byte offset
            __builtin_amdgcn_global_load_lds(
                (const __attribute__((address_space(1))) void*)(xq + (size_t)(m0 + row) * D + gcol),
                (__attribute__((address_space(3))) void*)(Al + lchunk), 16, 0, 0);
        }
        #pragma unroll
        for (int it = 0; it < 4; ++it) {     // B: 128 rows
            const int row    = it * 32 + row_s;
            const int gcol   = ((c8s ^ (row & 7)) * 16) + kt;
            const int lchunk = (it * 256 + t) * 16;
            __builtin_amdgcn_global_load_lds(
                (const __attribute__((address_space(1))) void*)(xq + (size_t)(n0 + row) * D + gcol),
                (__attribute__((address_space(3))) void*)(Bl + lchunk), 16, 0, 0);
        }
        __syncthreads();
        const int swz = c16 & 7;
        #pragma unroll
        for (int ks = 0; ks < 4; ++ks) {     // 4 x K=32 per BK=128
            long a[8], b[4];
            // lane's k-group: k = ks*32 + quad*8 + (0..7)  -> chunk (ks*2 + quad/2), byte (quad&1)*8
            const int cc = (((ks * 2 + (quad >> 1)) ^ swz) * 16) + (quad & 1) * 8;
            #pragma unroll
            for (int i = 0; i < 8; ++i)
                a[i] = *(const long*)(Al + (wrow + i * 16 + c16) * BK + cc);
            #pragma unroll
            for (int j = 0; j < 4; ++j)
                b[j] = *(const long*)(Bl + (wcol + j * 16 + c16) * BK + cc);
            #pragma unroll
            for (int i = 0; i < 8; ++i)
                #pragma unroll
                for (int j = 0; j < 4; ++j)
                    acc[i][j] = __builtin_amdgcn_mfma_f32_16x16x32_fp8_fp8(a[i], b[j], acc[i][j], 0, 0, 0);
        }
    }

    // ---- row-wise argmax (this wave's 128 rows, over its 64 cols) ----
    // C/D layout (m89-verified, dtype-independent): col = lane&15, row = quad*4 + reg.
    #pragma unroll
    for (int i = 0; i < 8; ++i) {
        #pragma unroll
        for (int r = 0; r < 4; ++r) {
            const int grow = m0 + wrow + i * 16 + quad * 4 + r;
            float v = -3.0f; unsigned c = 0xFFFFFFFFu;
            #pragma unroll
            for (int j = 0; j < 4; ++j) {
                const int col = n0 + wcol + j * 16 + c16;
                const float val = acc[i][j][r];
                if (col != grow && (val > v || (val == v && (unsigned)col < c))) {
                    v = val; c = (unsigned)col;
                }
            }
            // reduce across the quad's 16 lanes (one row lives in one quad)
            for (int off = 8; off; off >>= 1) {
                const float    ov = __shfl_xor(v, off);
                const unsigned oc = (unsigned)__shfl_xor((int)c, off);
                if (ov > v || (ov == v && oc < c)) { v = ov; c = oc; }
            }
            if (c16 == 0) atomicMax(best + grow, pack_key(v, c));
        }
    }

    // ---- col-wise argmax (this wave's 64 cols, over its 128 rows) ----
    #pragma unroll
    for (int j = 0; j < 4; ++j) {
        const int gcol = n0 + wcol + j * 16 + c16;
        float v = -3.0f; unsigned c = 0xFFFFFFFFu;
        #pragma unroll
        for (int i = 0; i < 8; ++i) {
            #pragma unroll
            for (int r = 0; r < 4; ++r) {
                const int grow = m0 + wrow + i * 16 + quad * 4 + r;
                const float val = acc[i][j][r];
                if (grow != gcol && (val > v || (val == v && (unsigned)grow < c))) {
                    v = val; c = (unsigned)grow;
                }
            }
        }
        // reduce across the 4 quads (lanes sharing c16): xor 16, 32
        for (int off = 32; off >= 16; off >>= 1) {
            const float    ov = __shfl_xor(v, off);
            const unsigned oc = (unsigned)__shfl_xor((int)c, off);
            if (ov > v || (ov == v && oc < c)) { v = ov; c = oc; }
        }
        if (quad == 0) atomicMax(best + gcol, pack_key(v, c));
    }
}

// ---------------- 3) pairwise distance + log -> 256 padded partials ---------
__global__ __launch_bounds__(256) void k_dist(
    const float* __restrict__ in, const float* __restrict__ norms,
    const unsigned long long* __restrict__ best, float* __restrict__ psum, int D)
{
    const int row = blockIdx.x;
    const int t = threadIdx.x;
    const unsigned long long key = best[row];
    const int nb = (int)(~(unsigned)key);        // recover neighbor index
    const float invi = 1.0f / fmaxf(norms[row], KEPS);
    const float invj = 1.0f / fmaxf(norms[nb], KEPS);
    const float4* xi = (const float4*)(in + (size_t)row * D);
    const float4* xj = (const float4*)(in + (size_t)nb * D);
    const float4 a = xi[t], b = xj[t];
    const float dx = a.x * invi - b.x * invj + KEPS;
    const float dy = a.y * invi - b.y * invj + KEPS;
    const float dz = a.z * invi - b.z * invj + KEPS;
    const float dw = a.w * invi - b.w * invj + KEPS;
    float ss = dx*dx + dy*dy + dz*dz + dw*dw;
    for (int off = 32; off; off >>= 1) ss += __shfl_down(ss, off);
    __shared__ float red[4];
    const int lane = t & 63, wave = t >> 6;
    if (lane == 0) red[wave] = ss;
    __syncthreads();
    if (t == 0) {
        const float tot = red[0] + red[1] + red[2] + red[3];
        // scatter over 256 cache-line-padded slots: 64 atomics/slot, no hotspot
        atomicAdd(psum + (row & 255) * 16, logf(sqrtf(tot) + KEPS));
    }
}

// ---------------- 4) finalize: reduce 256 partials --------------------------
__global__ void k_final(const float* __restrict__ psum, float* __restrict__ out, float invN)
{
    const int t = threadIdx.x;                   // 64 threads
    float s = psum[t * 16] + psum[(t + 64) * 16]
            + psum[(t + 128) * 16] + psum[(t + 192) * 16];
    for (int off = 32; off; off >>= 1) s += __shfl_down(s, off);
    if (t == 0) out[0] = -s * invN;
}

extern "C" void kernel_launch(void* const* d_in, const int* in_sizes, int n_in,
                              void* d_out, int out_size, void* d_ws, size_t ws_size,
                              hipStream_t stream)
{
    const float* in = (const float*)d_in[0];
    const int D = 1024;
    const int N = in_sizes[0] / D;               // 16384

    char* ws = (char*)d_ws;
    uchar* xq = (uchar*)ws;                                      // N*D     = 16 MiB
    size_t off = (size_t)N * D;
    float* norms = (float*)(ws + off);           off += (size_t)N * 4;
    unsigned long long* best = (unsigned long long*)(ws + off); off += (size_t)N * 8;
    float* psum = (float*)(ws + off);            // 256 slots x 16 floats = 16 KiB
    float* out = (float*)d_out;

    k_normalize<<<N, 256, 0, stream>>>(in, xq, norms, best, psum, D);
    const int TY = N / BM;                       // 64 row-tiles
    const int TX = N / BN;                       // 128 col-tiles
    int P = 0;
    for (int by = 0; by < TY; ++by) P += TX - 2 * by;   // 4160 blocks
    k_gemm_argmax<<<P, 256, 0, stream>>>(xq, best, N, D, TX);
    k_dist<<<N, 256, 0, stream>>>(in, norms, best, psum, D);
    k_final<<<1, 64, 0, stream>>>(psum, out, 1.0f / (float)N);
}